// Round 1
// baseline (476.834 us; speedup 1.0000x reference)
//
#include <hip/hip_runtime.h>

#define NPOS 8192
#define NC 64
#define SCALE 0.0078125f

typedef __bf16 bf16x8 __attribute__((ext_vector_type(8)));
typedef float f32x4 __attribute__((ext_vector_type(4)));

static __device__ __forceinline__ unsigned f2bf_u(float x) {
  unsigned u = __float_as_uint(x);
  return (u + 0x7FFFu + ((u >> 16) & 1u)) >> 16;
}
static __device__ __forceinline__ unsigned pack2(float a, float b) {
  return f2bf_u(a) | (f2bf_u(b) << 16);
}

// Stage 1: 1x1 conv projections. q,k -> [B][N][C] bf16 (position-major),
// v -> [B][C][N] bf16 + fp32.
__global__ __launch_bounds__(256) void proj_kernel(
    const float* __restrict__ xq, const float* __restrict__ xk, const float* __restrict__ xv,
    const float* __restrict__ Wq, const float* __restrict__ bq,
    const float* __restrict__ Wk, const float* __restrict__ bk,
    const float* __restrict__ Wv, const float* __restrict__ bv,
    unsigned short* __restrict__ qT, unsigned short* __restrict__ kT,
    unsigned short* __restrict__ vb, float* __restrict__ vf)
{
  __shared__ float sW[NC * NC];
  __shared__ float sB[NC];
  const int p = blockIdx.z, b = blockIdx.y;
  const int n0 = blockIdx.x * 256;
  const int tid = threadIdx.x;
  const int wv = tid >> 6, l = tid & 63;

  const float* x    = p == 0 ? xq : (p == 1 ? xk : xv);
  const float* W    = p == 0 ? Wq : (p == 1 ? Wk : Wv);
  const float* bias = p == 0 ? bq : (p == 1 ? bk : bv);

  for (int i = tid; i < NC * NC; i += 256) sW[i] = W[i];
  if (tid < NC) sB[tid] = bias[tid];
  __syncthreads();

  const int nb = n0 + 4 * l;  // this thread's 4 consecutive positions
  const float* xb = x + (size_t)b * NC * NPOS + nb;

  float acc[16][4];
#pragma unroll
  for (int oi = 0; oi < 16; ++oi) {
    float bz = sB[16 * wv + oi];
    acc[oi][0] = bz; acc[oi][1] = bz; acc[oi][2] = bz; acc[oi][3] = bz;
  }
  for (int c = 0; c < NC; ++c) {
    const float4 x4 = *(const float4*)(xb + (size_t)c * NPOS);
#pragma unroll
    for (int oi = 0; oi < 16; ++oi) {
      float wgt = sW[(16 * wv + oi) * NC + c];
      acc[oi][0] = fmaf(wgt, x4.x, acc[oi][0]);
      acc[oi][1] = fmaf(wgt, x4.y, acc[oi][1]);
      acc[oi][2] = fmaf(wgt, x4.z, acc[oi][2]);
      acc[oi][3] = fmaf(wgt, x4.w, acc[oi][3]);
    }
  }

  if (p < 2) {
    unsigned short* dst = (p == 0 ? qT : kT) + (size_t)b * NPOS * NC;
#pragma unroll
    for (int r = 0; r < 4; ++r) {
      uint4 w0, w1;
      w0.x = pack2(acc[0][r],  acc[1][r]);
      w0.y = pack2(acc[2][r],  acc[3][r]);
      w0.z = pack2(acc[4][r],  acc[5][r]);
      w0.w = pack2(acc[6][r],  acc[7][r]);
      w1.x = pack2(acc[8][r],  acc[9][r]);
      w1.y = pack2(acc[10][r], acc[11][r]);
      w1.z = pack2(acc[12][r], acc[13][r]);
      w1.w = pack2(acc[14][r], acc[15][r]);
      unsigned short* rp = dst + (size_t)(nb + r) * NC + 16 * wv;
      *(uint4*)(rp) = w0;
      *(uint4*)(rp + 8) = w1;
    }
  } else {
#pragma unroll
    for (int oi = 0; oi < 16; ++oi) {
      const int o = 16 * wv + oi;
      float4 v4;
      v4.x = acc[oi][0]; v4.y = acc[oi][1]; v4.z = acc[oi][2]; v4.w = acc[oi][3];
      *(float4*)(vf + ((size_t)b * NC + o) * NPOS + nb) = v4;
      uint2 u2;
      u2.x = pack2(acc[oi][0], acc[oi][1]);
      u2.y = pack2(acc[oi][2], acc[oi][3]);
      *(uint2*)(vb + ((size_t)b * NC + o) * NPOS + nb) = u2;
    }
  }
}

// Stage 2: flash attention over n for each output column m.
// Block = (b, 64 columns); wave w owns 16 columns. No __syncthreads in loop.
__global__ __launch_bounds__(256) void attn_kernel(
    const unsigned short* __restrict__ qT,
    const unsigned short* __restrict__ kT,
    const unsigned short* __restrict__ vb,
    const float* __restrict__ vf,
    const float* __restrict__ gamma_p,
    float* __restrict__ out)
{
  __shared__ unsigned short pT[4][16][72];  // per-wave P^T staging, padded stride
  const int b  = blockIdx.y;
  const int m0 = blockIdx.x * 64;
  const int tid = threadIdx.x;
  const int w = tid >> 6, l = tid & 63;
  const int lm = l & 15, g = l >> 4;
  const int m = m0 + 16 * w + lm;  // this lane's output column

  // K fragments: constant over the whole n-loop (B operand, col = m)
  const unsigned short* kb_p = kT + (size_t)(b * NPOS + m) * NC + 8 * g;
  const bf16x8 kb0 = *(const bf16x8*)(kb_p);
  const bf16x8 kb1 = *(const bf16x8*)(kb_p + 32);

  const unsigned short* qb  = qT + (size_t)b * NPOS * NC;
  const unsigned short* vbb = vb + (size_t)b * NC * NPOS;

  f32x4 acc[4] = {{0,0,0,0},{0,0,0,0},{0,0,0,0},{0,0,0,0}};
  float lsum = 0.f;

  for (int n0 = 0; n0 < NPOS; n0 += 64) {
    // QK^T: S'[n][m], 4 n-subtiles of 16, K-dim = 64 channels = 2 MFMA each
    f32x4 s[4];
#pragma unroll
    for (int sub = 0; sub < 4; ++sub) {
      const unsigned short* qrow = qb + (size_t)(n0 + 16 * sub + lm) * NC + 8 * g;
      bf16x8 qa0 = *(const bf16x8*)(qrow);
      bf16x8 qa1 = *(const bf16x8*)(qrow + 32);
      f32x4 z = {0, 0, 0, 0};
      z = __builtin_amdgcn_mfma_f32_16x16x32_bf16(qa0, kb0, z, 0, 0, 0);
      z = __builtin_amdgcn_mfma_f32_16x16x32_bf16(qa1, kb1, z, 0, 0, 0);
      s[sub] = z;
    }
    // softmax weights, no max-subtraction (scores bounded ~|0.4|)
#pragma unroll
    for (int sub = 0; sub < 4; ++sub) {
      float p0 = __expf(s[sub][0] * SCALE);
      float p1 = __expf(s[sub][1] * SCALE);
      float p2 = __expf(s[sub][2] * SCALE);
      float p3 = __expf(s[sub][3] * SCALE);
      lsum += (p0 + p1) + (p2 + p3);
      uint2 u;
      u.x = pack2(p0, p1);
      u.y = pack2(p2, p3);
      // rows n_loc = 16*sub + 4*g + {0..3}, column lm
      *(uint2*)&pT[w][lm][16 * sub + 4 * g] = u;
    }
    // PV: av[c][m] += V[c][n] * P[n][m]
#pragma unroll
    for (int ks = 0; ks < 2; ++ks) {
      bf16x8 pb = *(const bf16x8*)&pT[w][lm][8 * g + 32 * ks];
#pragma unroll
      for (int cs = 0; cs < 4; ++cs) {
        const unsigned short* vrow =
            vbb + (size_t)(16 * cs + lm) * NPOS + n0 + 8 * g + 32 * ks;
        bf16x8 va = *(const bf16x8*)(vrow);
        acc[cs] = __builtin_amdgcn_mfma_f32_16x16x32_bf16(va, pb, acc[cs], 0, 0, 0);
      }
    }
  }

  // finalize: total denominator per column (reduce over the 4 lane groups)
  lsum += __shfl_xor(lsum, 16);
  lsum += __shfl_xor(lsum, 32);
  const float gs = gamma_p[0] / lsum;

  const size_t ob = (size_t)b * NC * NPOS;
#pragma unroll
  for (int cs = 0; cs < 4; ++cs) {
#pragma unroll
    for (int r = 0; r < 4; ++r) {
      const int c = 16 * cs + 4 * g + r;
      const size_t idx = ob + (size_t)c * NPOS + m;
      out[idx] = gs * acc[cs][r] + vf[idx];
    }
  }
}

extern "C" void kernel_launch(void* const* d_in, const int* in_sizes, int n_in,
                              void* d_out, int out_size, void* d_ws, size_t ws_size,
                              hipStream_t stream) {
  const float* xq = (const float*)d_in[0];
  const float* xk = (const float*)d_in[1];
  const float* xv = (const float*)d_in[2];
  const float* Wq = (const float*)d_in[3];
  const float* bq = (const float*)d_in[4];
  const float* Wk = (const float*)d_in[5];
  const float* bk = (const float*)d_in[6];
  const float* Wv = (const float*)d_in[7];
  const float* bv = (const float*)d_in[8];
  const float* gm = (const float*)d_in[9];
  float* out = (float*)d_out;

  // workspace: qT(4MB) | kT(4MB) | v_bf16(4MB) | v_f32(8MB) = 20MB
  unsigned short* qT   = (unsigned short*)d_ws;
  unsigned short* kT   = qT + (size_t)4 * NPOS * NC;
  unsigned short* vbuf = kT + (size_t)4 * NPOS * NC;
  float* vf = (float*)(vbuf + (size_t)4 * NPOS * NC);

  hipLaunchKernelGGL(proj_kernel, dim3(32, 4, 3), dim3(256), 0, stream,
                     xq, xk, xv, Wq, bq, Wk, bk, Wv, bv, qT, kT, vbuf, vf);
  hipLaunchKernelGGL(attn_kernel, dim3(128, 4), dim3(256), 0, stream,
                     qT, kT, vbuf, vf, gm, out);
}